// Round 1
// baseline (168.541 us; speedup 1.0000x reference)
//
#include <hip/hip_runtime.h>
#include <math.h>

#define B 384
#define C 512
#define NPAIR (B * B)          // 147456
#define NOFF  (B * (B - 1))    // 147072

// ws layout (floats):
// [0..15] accum: 0 hard_sum, 1 sumd_s, 2 sumd_t, 3 dist_am, 4 dist_m2, 5 ang_am, 6 ang_m2
#define PS_OFF  16
#define PT_OFF  (16 + NPAIR)
#define SQS_OFF (16 + 2 * NPAIR)
#define SQT_OFF (SQS_OFF + B)
// total = 295696 floats = 1.18 MB

__device__ __forceinline__ float blk_sum(float v, float* s4, int t) {
#pragma unroll
  for (int off = 32; off > 0; off >>= 1) v += __shfl_down(v, off, 64);
  if ((t & 63) == 0) s4[t >> 6] = v;
  __syncthreads();
  float r = s4[0] + s4[1] + s4[2] + s4[3];
  __syncthreads();
  return r;
}

// K1: per-row squared norms (s and t) + CE loss contribution
__global__ __launch_bounds__(256) void k_row(const float* __restrict__ fs,
                                             const float* __restrict__ ft,
                                             const int* __restrict__ lab,
                                             float* __restrict__ ws) {
  int r = blockIdx.x, t = threadIdx.x;
  const float* xs = fs + r * C;
  const float* xt = ft + r * C;
  float x0 = xs[t], x1 = xs[t + 256];
  float y0 = xt[t], y1 = xt[t + 256];
  __shared__ float s4[4];
  float m = fmaxf(x0, x1);
#pragma unroll
  for (int off = 32; off > 0; off >>= 1) m = fmaxf(m, __shfl_down(m, off, 64));
  if ((t & 63) == 0) s4[t >> 6] = m;
  __syncthreads();
  m = fmaxf(fmaxf(s4[0], s4[1]), fmaxf(s4[2], s4[3]));
  __syncthreads();
  float es = blk_sum(expf(x0 - m) + expf(x1 - m), s4, t);
  float ss = blk_sum(x0 * x0 + x1 * x1, s4, t);
  float st = blk_sum(y0 * y0 + y1 * y1, s4, t);
  if (t == 0) {
    ws[SQS_OFF + r] = ss;
    ws[SQT_OFF + r] = st;
    float hard = m + logf(es) - xs[lab[r]];
    atomicAdd(ws, hard);
  }
}

// K2: P = F F^T (fp32, 64x64 tile, 4x4 micro, k-split 4 via atomics)
__global__ __launch_bounds__(256) void k_gram(const float* __restrict__ fs,
                                              const float* __restrict__ ft,
                                              float* __restrict__ ws) {
  int tensor = blockIdx.z >> 2;
  int k0 = (blockIdx.z & 3) * 128;
  const float* F = tensor ? ft : fs;
  float* P = ws + (tensor ? PT_OFF : PS_OFF);
  int i0 = blockIdx.x * 64, j0 = blockIdx.y * 64;
  __shared__ float As[64][36];  // stride 36: 16B-aligned rows, conflict-benign
  __shared__ float Bs[64][36];
  int t = threadIdx.x;
  int ty = t >> 4, tx = t & 15;
  int lrow = t >> 3, lc = (t & 7) * 4;
  float acc[4][4] = {};
  for (int s = 0; s < 4; ++s) {
    int kk = k0 + s * 32;
    __syncthreads();
    float4 a0 = *(const float4*)&F[(i0 + lrow) * C + kk + lc];
    float4 a1 = *(const float4*)&F[(i0 + lrow + 32) * C + kk + lc];
    float4 b0 = *(const float4*)&F[(j0 + lrow) * C + kk + lc];
    float4 b1 = *(const float4*)&F[(j0 + lrow + 32) * C + kk + lc];
    *(float4*)&As[lrow][lc] = a0;
    *(float4*)&As[lrow + 32][lc] = a1;
    *(float4*)&Bs[lrow][lc] = b0;
    *(float4*)&Bs[lrow + 32][lc] = b1;
    __syncthreads();
#pragma unroll
    for (int k4 = 0; k4 < 8; ++k4) {
      float4 av[4], bv[4];
#pragma unroll
      for (int r = 0; r < 4; ++r) av[r] = *(const float4*)&As[ty * 4 + r][k4 * 4];
#pragma unroll
      for (int c = 0; c < 4; ++c) bv[c] = *(const float4*)&Bs[tx * 4 + c][k4 * 4];
#pragma unroll
      for (int r = 0; r < 4; ++r)
#pragma unroll
        for (int c = 0; c < 4; ++c)
          acc[r][c] += av[r].x * bv[c].x + av[r].y * bv[c].y +
                       av[r].z * bv[c].z + av[r].w * bv[c].w;
    }
  }
#pragma unroll
  for (int r = 0; r < 4; ++r)
#pragma unroll
    for (int c = 0; c < 4; ++c)
      atomicAdd(&P[(i0 + ty * 4 + r) * B + j0 + tx * 4 + c], acc[r][c]);
}

// K2b: sum of off-diagonal distances per tensor (for mean_pos)
__global__ __launch_bounds__(256) void k_dsum(float* __restrict__ ws) {
  int tensor = blockIdx.y;
  const float* P = ws + (tensor ? PT_OFF : PS_OFF);
  const float* sq = ws + (tensor ? SQT_OFF : SQS_OFF);
  int e = blockIdx.x * 256 + threadIdx.x;
  int b = e / B, i = e - b * B;
  float d2 = sq[b] + sq[i] - 2.f * P[e];
  float d = (b == i) ? 0.f : sqrtf(fmaxf(d2, 1e-12f));
  __shared__ float s4[4];
  float tot = blk_sum(d, s4, threadIdx.x);
  if (threadIdx.x == 0) atomicAdd(ws + 1 + tensor, tot);
}

// K3: distance-huber partial sums
__global__ __launch_bounds__(256) void k_dist(float* __restrict__ ws) {
  const float* Ps = ws + PS_OFF;
  const float* Pt = ws + PT_OFF;
  const float* sqs = ws + SQS_OFF;
  const float* sqt = ws + SQT_OFF;
  float inv_ms = (float)NOFF / ws[1];
  float inv_mt = (float)NOFF / ws[2];
  int e = blockIdx.x * 256 + threadIdx.x;
  int b = e / B, i = e - b * B;
  float d2s = sqs[b] + sqs[i] - 2.f * Ps[e];
  float d2t = sqt[b] + sqt[i] - 2.f * Pt[e];
  float ds = (b == i) ? 0.f : sqrtf(fmaxf(d2s, 1e-12f)) * inv_ms;
  float dt = (b == i) ? 0.f : sqrtf(fmaxf(d2t, 1e-12f)) * inv_mt;
  float a = fabsf(ds - dt);
  float mm = fminf(a, 1.f);
  __shared__ float s4[4];
  float am = blk_sum(a * mm, s4, threadIdx.x);
  float m2 = blk_sum(mm * mm, s4, threadIdx.x);
  if (threadIdx.x == 0) { atomicAdd(ws + 3, am); atomicAdd(ws + 4, m2); }
}

// K4: angle-huber over B^3 via Gram identity.
// Block: 128(i) x 64(j) tile, 8 b's staged; thread: 8x4 micro-tile.
#define BCH 8
__global__ __launch_bounds__(256) void k_angle(float* __restrict__ ws) {
  const float* Ps = ws + PS_OFF;
  const float* Pt = ws + PT_OFF;
  const float* sqs = ws + SQS_OFF;
  const float* sqt = ws + SQT_OFF;
  int it = blockIdx.x / 6, jt = blockIdx.x % 6;
  int i0 = it * 128, j0 = jt * 64;
  int b0 = blockIdx.y * BCH;
  int t = threadIdx.x;
  int ty = t >> 4, tx = t & 15;  // i = ty*8+r, j = tx*4+c

  __shared__ float sI[BCH][4][128];  // [b][us,vs,ut,vt][i]
  __shared__ float sJ[BCH][4][64];
  __shared__ float s4[4];

  float ps[8][4], pt[8][4];
#pragma unroll
  for (int r = 0; r < 8; ++r) {
    float4 v = *(const float4*)&Ps[(i0 + ty * 8 + r) * B + j0 + tx * 4];
    ps[r][0] = v.x; ps[r][1] = v.y; ps[r][2] = v.z; ps[r][3] = v.w;
    v = *(const float4*)&Pt[(i0 + ty * 8 + r) * B + j0 + tx * 4];
    pt[r][0] = v.x; pt[r][1] = v.y; pt[r][2] = v.z; pt[r][3] = v.w;
  }

  // stage u/v (computed on the fly from P, sq — never materialized in HBM)
  for (int idx = t; idx < BCH * 192; idx += 256) {
    int b = idx / 192, p = idx - (idx / 192) * 192;
    int bb = b0 + b;
    float pbbs = Ps[bb * B + bb];
    float pbbt = Pt[bb * B + bb];
    float sqbs = sqs[bb], sqbt = sqt[bb];
    int col = (p < 128) ? (i0 + p) : (j0 + p - 128);
    float pvs = Ps[bb * B + col];
    float pvt = Pt[bb * B + col];
    float d2s = sqbs + sqs[col] - 2.f * pvs;
    float d2t = sqbt + sqt[col] - 2.f * pvt;
    float us = (col == bb) ? 0.f : 1.f / fmaxf(sqrtf(fmaxf(d2s, 0.f)), 1e-12f);
    float ut = (col == bb) ? 0.f : 1.f / fmaxf(sqrtf(fmaxf(d2t, 0.f)), 1e-12f);
    float vs = pvs - 0.5f * pbbs;
    float vt = pvt - 0.5f * pbbt;
    if (p < 128) {
      sI[b][0][p] = us; sI[b][1][p] = vs; sI[b][2][p] = ut; sI[b][3][p] = vt;
    } else {
      int q = p - 128;
      sJ[b][0][q] = us; sJ[b][1][q] = vs; sJ[b][2][q] = ut; sJ[b][3][q] = vt;
    }
  }
  __syncthreads();

  float accA = 0.f, accM = 0.f;
  for (int b = 0; b < BCH; ++b) {
    float uis[8], vis[8], uit[8], vit[8];
    float ujs[4], vjs[4], ujt[4], vjt[4];
    *(float4*)&uis[0] = *(const float4*)&sI[b][0][ty * 8];
    *(float4*)&uis[4] = *(const float4*)&sI[b][0][ty * 8 + 4];
    *(float4*)&vis[0] = *(const float4*)&sI[b][1][ty * 8];
    *(float4*)&vis[4] = *(const float4*)&sI[b][1][ty * 8 + 4];
    *(float4*)&uit[0] = *(const float4*)&sI[b][2][ty * 8];
    *(float4*)&uit[4] = *(const float4*)&sI[b][2][ty * 8 + 4];
    *(float4*)&vit[0] = *(const float4*)&sI[b][3][ty * 8];
    *(float4*)&vit[4] = *(const float4*)&sI[b][3][ty * 8 + 4];
    *(float4*)&ujs[0] = *(const float4*)&sJ[b][0][tx * 4];
    *(float4*)&vjs[0] = *(const float4*)&sJ[b][1][tx * 4];
    *(float4*)&ujt[0] = *(const float4*)&sJ[b][2][tx * 4];
    *(float4*)&vjt[0] = *(const float4*)&sJ[b][3][tx * 4];
#pragma unroll
    for (int r = 0; r < 8; ++r)
#pragma unroll
      for (int c = 0; c < 4; ++c) {
        float gs = uis[r] * ujs[c] * (ps[r][c] - vis[r] - vjs[c]);
        float gt = uit[r] * ujt[c] * (pt[r][c] - vit[r] - vjt[c]);
        float a = fabsf(gs - gt);
        float mm = fminf(a, 1.f);
        accA = fmaf(a, mm, accA);   // sum a*min(a,1)
        accM = fmaf(mm, mm, accM);  // sum min(a,1)^2 ; huber = accA - 0.5*accM
      }
  }
  float am = blk_sum(accA, s4, t);
  float m2 = blk_sum(accM, s4, t);
  if (t == 0) { atomicAdd(ws + 5, am); atomicAdd(ws + 6, m2); }
}

// K5: combine
__global__ void k_final(const float* __restrict__ ws, float* __restrict__ out) {
  if (threadIdx.x == 0) {
    float hard = ws[0] * (1.0f / (float)B);
    float dist = (ws[3] - 0.5f * ws[4]) * (1.0f / (float)NPAIR);
    float ang  = (ws[5] - 0.5f * ws[6]) * (1.0f / 56623104.0f);  // 384^3
    out[0] = hard + dist + ang;
  }
}

extern "C" void kernel_launch(void* const* d_in, const int* in_sizes, int n_in,
                              void* d_out, int out_size, void* d_ws, size_t ws_size,
                              hipStream_t stream) {
  (void)in_sizes; (void)n_in; (void)out_size; (void)ws_size;
  const float* fs = (const float*)d_in[0];
  const float* ft = (const float*)d_in[1];
  const int* lab = (const int*)d_in[2];
  float* ws = (float*)d_ws;
  float* out = (float*)d_out;

  // zero accumulators + P buffers (atomically accumulated)
  hipMemsetAsync(d_ws, 0, (size_t)(16 + 2 * NPAIR) * sizeof(float), stream);

  k_row<<<B, 256, 0, stream>>>(fs, ft, lab, ws);
  k_gram<<<dim3(6, 6, 8), 256, 0, stream>>>(fs, ft, ws);
  k_dsum<<<dim3(NPAIR / 256, 2), 256, 0, stream>>>(ws);
  k_dist<<<NPAIR / 256, 256, 0, stream>>>(ws);
  k_angle<<<dim3(18, 48), 256, 0, stream>>>(ws);
  k_final<<<1, 64, 0, stream>>>(ws, out);
}

// Round 2
// 86.670 us; speedup vs baseline: 1.9446x; 1.9446x over previous
//
#include <hip/hip_runtime.h>
#include <hip/hip_bf16.h>
#include <math.h>

#define B 384
#define C 512
#define NPAIR (B * B)          // 147456
#define NOFF  (B * (B - 1))    // 147072

#define T16  24   // 16x16 tiles per dim in gram
#define UP16 300  // upper-incl-diag tile count (24*25/2)
#define T64  6    // 64x64 tiles per dim in angle
#define UP64 21   // 6*7/2

// ws layout (floats) — every slot written before read within one launch; no zero-init needed.
#define HARD_OFF 0            // 384: per-row CE
#define DSUM_OFF 384          // 600: per-gram-wave weighted d-sums (s: [0,300), t: [300,600))
#define ANG_OFF  984          // 1008: per-angle-block huber partials
#define DIST_OFF 1992         // 21: per-(y==0)-angle-block dist-huber partials
#define SQS_OFF  2016         // 384
#define SQT_OFF  2400         // 384
#define PS_OFF   2816         // 147456 (16B-aligned)
#define PT_OFF   (PS_OFF + NPAIR)
// total = PT_OFF + NPAIR = 297728 floats ≈ 1.14 MB

typedef __attribute__((ext_vector_type(8))) short short8;
typedef __attribute__((ext_vector_type(4))) float floatx4;

__device__ __forceinline__ float blk_sum(float v, float* s4, int t) {
#pragma unroll
  for (int off = 32; off > 0; off >>= 1) v += __shfl_down(v, off, 64);
  if ((t & 63) == 0) s4[t >> 6] = v;
  __syncthreads();
  float r = s4[0] + s4[1] + s4[2] + s4[3];
  __syncthreads();
  return r;
}

__device__ __forceinline__ short bfc(float x) {
  __hip_bfloat16 h = __float2bfloat16(x);
  return __builtin_bit_cast(short, h);
}

__device__ __forceinline__ short8 load_frag(const float* p) {
  float4 lo = *(const float4*)p;
  float4 hi = *(const float4*)(p + 4);
  short8 v;
  v[0] = bfc(lo.x); v[1] = bfc(lo.y); v[2] = bfc(lo.z); v[3] = bfc(lo.w);
  v[4] = bfc(hi.x); v[5] = bfc(hi.y); v[6] = bfc(hi.z); v[7] = bfc(hi.w);
  return v;
}

// K1: per-row sq norms (s,t) + per-row CE (no atomics)
__global__ __launch_bounds__(256) void k_row(const float* __restrict__ fs,
                                             const float* __restrict__ ft,
                                             const int* __restrict__ lab,
                                             float* __restrict__ ws) {
  int r = blockIdx.x, t = threadIdx.x;
  const float* xs = fs + r * C;
  const float* xt = ft + r * C;
  float x0 = xs[t], x1 = xs[t + 256];
  float y0 = xt[t], y1 = xt[t + 256];
  __shared__ float s4[4];
  float m = fmaxf(x0, x1);
#pragma unroll
  for (int off = 32; off > 0; off >>= 1) m = fmaxf(m, __shfl_down(m, off, 64));
  if ((t & 63) == 0) s4[t >> 6] = m;
  __syncthreads();
  m = fmaxf(fmaxf(s4[0], s4[1]), fmaxf(s4[2], s4[3]));
  __syncthreads();
  float es = blk_sum(expf(x0 - m) + expf(x1 - m), s4, t);
  float ss = blk_sum(x0 * x0 + x1 * x1, s4, t);
  float st = blk_sum(y0 * y0 + y1 * y1, s4, t);
  if (t == 0) {
    ws[SQS_OFF + r] = ss;
    ws[SQT_OFF + r] = st;
    ws[HARD_OFF + r] = m + logf(es) - xs[lab[r]];
  }
}

// K2: P = F F^T via bf16 MFMA 16x16x32, one 16x16 tile per wave, upper tiles only,
// symmetric store; epilogue accumulates weighted off-diag distance sum per wave slot.
__global__ __launch_bounds__(256, 4) void k_gram(const float* __restrict__ fs,
                                                 const float* __restrict__ ft,
                                                 float* __restrict__ ws) {
  int t = threadIdx.x;
  int w = t >> 6, lane = t & 63;
  int g = blockIdx.x * 4 + w;        // [0, 600)
  int tensor = (g >= UP16) ? 1 : 0;
  int uu = g - tensor * UP16;
  int ti = 0;
  while (uu >= T16 - ti) { uu -= T16 - ti; ++ti; }
  int tj = ti + uu;
  const float* F = tensor ? ft : fs;
  const float* sq = ws + (tensor ? SQT_OFF : SQS_OFF);
  float* P = ws + (tensor ? PT_OFF : PS_OFF);
  int i0 = ti * 16, j0 = tj * 16;
  int r = lane & 15, q = lane >> 4;
  // A[m=lane&15][k=quad*8+j], B[k=quad*8+j][n=lane&15] (m89-verified mapping)
  const float* arow = F + (i0 + r) * C + q * 8;
  const float* brow = F + (j0 + r) * C + q * 8;
  floatx4 acc = {0.f, 0.f, 0.f, 0.f};
#pragma unroll
  for (int ks = 0; ks < 16; ++ks) {
    short8 a = load_frag(arow + ks * 32);
    short8 b = load_frag(brow + ks * 32);
    acc = __builtin_amdgcn_mfma_f32_16x16x32_bf16(a, b, acc, 0, 0, 0);
  }
  // C/D layout: col = lane&15, row = quad*4 + reg
  int col = lane & 15;
  int j = j0 + col;
  float sqj = sq[j];
  float dsum = 0.f;
#pragma unroll
  for (int reg = 0; reg < 4; ++reg) {
    int i = i0 + q * 4 + reg;
    float p = acc[reg];
    P[i * B + j] = p;
    P[j * B + i] = p;   // symmetric mirror (diag tile: identical value, benign)
    float d2 = sq[i] + sqj - 2.f * p;
    float d = sqrtf(fmaxf(d2, 1e-12f));
    float wgt = (ti < tj) ? 2.f : ((i < j) ? 2.f : 0.f);
    dsum = fmaf(wgt, d, dsum);
  }
#pragma unroll
  for (int off = 32; off > 0; off >>= 1) dsum += __shfl_down(dsum, off, 64);
  if (lane == 0) ws[DSUM_OFF + g] = dsum;
}

// K3: angle-huber over upper-triangle (i,j) tiles via Gram identity; dist-huber fused
// into y==0 blocks. gs = uj*(fma(ui,P,-qi)) - ui*qj with q=u*v.
#define BCH 8
#define ANGLE_BODY(MASKED)                                                   \
  for (int b = 0; b < BCH; ++b) {                                            \
    float uis[4], qis[4], uit[4], qit[4], ujs[4], qjs[4], ujt[4], qjt[4];    \
    float4 v;                                                                \
    v = *(const float4*)&sI[b][0][ty * 4];                                   \
    uis[0] = v.x; uis[1] = v.y; uis[2] = v.z; uis[3] = v.w;                  \
    v = *(const float4*)&sI[b][1][ty * 4];                                   \
    qis[0] = v.x; qis[1] = v.y; qis[2] = v.z; qis[3] = v.w;                  \
    v = *(const float4*)&sI[b][2][ty * 4];                                   \
    uit[0] = v.x; uit[1] = v.y; uit[2] = v.z; uit[3] = v.w;                  \
    v = *(const float4*)&sI[b][3][ty * 4];                                   \
    qit[0] = v.x; qit[1] = v.y; qit[2] = v.z; qit[3] = v.w;                  \
    v = *(const float4*)&sJ[b][0][tx * 4];                                   \
    ujs[0] = v.x; ujs[1] = v.y; ujs[2] = v.z; ujs[3] = v.w;                  \
    v = *(const float4*)&sJ[b][1][tx * 4];                                   \
    qjs[0] = v.x; qjs[1] = v.y; qjs[2] = v.z; qjs[3] = v.w;                  \
    v = *(const float4*)&sJ[b][2][tx * 4];                                   \
    ujt[0] = v.x; ujt[1] = v.y; ujt[2] = v.z; ujt[3] = v.w;                  \
    v = *(const float4*)&sJ[b][3][tx * 4];                                   \
    qjt[0] = v.x; qjt[1] = v.y; qjt[2] = v.z; qjt[3] = v.w;                  \
    _Pragma("unroll")                                                        \
    for (int r = 0; r < 4; ++r) {                                            \
      _Pragma("unroll")                                                      \
      for (int c = 0; c < 4; ++c) {                                          \
        float f1s = fmaf(uis[r], ps[r][c], -qis[r]);                         \
        float gs = fmaf(ujs[c], f1s, -(uis[r] * qjs[c]));                    \
        float f1t = fmaf(uit[r], pt[r][c], -qit[r]);                         \
        float gt = fmaf(ujt[c], f1t, -(uit[r] * qjt[c]));                    \
        float a = fabsf(gs - gt);                                            \
        if (MASKED) a = (ty * 4 + r < tx * 4 + c) ? a : 0.f;                 \
        float mm = fminf(a, 1.f);                                            \
        acc = fmaf(mm, fmaf(-0.5f, mm, a), acc);                             \
      }                                                                      \
    }                                                                        \
  }

__global__ __launch_bounds__(256, 4) void k_angle(float* __restrict__ ws) {
  const float* Ps = ws + PS_OFF;
  const float* Pt = ws + PT_OFF;
  const float* sqs = ws + SQS_OFF;
  const float* sqt = ws + SQT_OFF;
  int uu = blockIdx.x;
  int ti = 0;
  while (uu >= T64 - ti) { uu -= T64 - ti; ++ti; }
  int tj = ti + uu;
  int i0 = ti * 64, j0 = tj * 64;
  bool diag = (ti == tj);
  int b0 = blockIdx.y * BCH;
  int t = threadIdx.x;
  int ty = t >> 4, tx = t & 15;

  __shared__ float sI[BCH][4][64];  // planes: us, qs, ut, qt
  __shared__ float sJ[BCH][4][64];
  __shared__ float s4[4];

  float ps[4][4], pt[4][4];
#pragma unroll
  for (int r = 0; r < 4; ++r) {
    float4 v = *(const float4*)&Ps[(i0 + ty * 4 + r) * B + j0 + tx * 4];
    ps[r][0] = v.x; ps[r][1] = v.y; ps[r][2] = v.z; ps[r][3] = v.w;
    v = *(const float4*)&Pt[(i0 + ty * 4 + r) * B + j0 + tx * 4];
    pt[r][0] = v.x; pt[r][1] = v.y; pt[r][2] = v.z; pt[r][3] = v.w;
  }

  for (int idx = t; idx < BCH * 128; idx += 256) {
    int b = idx >> 7, p = idx & 127;
    int bb = b0 + b;
    int col = (p < 64) ? (i0 + p) : (j0 + p - 64);
    float pvs = Ps[bb * B + col];
    float pvt = Pt[bb * B + col];
    float pbbs = Ps[bb * B + bb];
    float pbbt = Pt[bb * B + bb];
    float d2s = sqs[bb] + sqs[col] - 2.f * pvs;
    float d2t = sqt[bb] + sqt[col] - 2.f * pvt;
    float us = (col == bb) ? 0.f : rsqrtf(fmaxf(d2s, 1e-24f));
    float ut = (col == bb) ? 0.f : rsqrtf(fmaxf(d2t, 1e-24f));
    float qs = us * (pvs - 0.5f * pbbs);
    float qt = ut * (pvt - 0.5f * pbbt);
    float* dst = (p < 64) ? &sI[b][0][p] : &sJ[b][0][p - 64];
    dst[0] = us; dst[64] = qs; dst[128] = ut; dst[192] = qt;
  }
  __syncthreads();

  float acc = 0.f;
  if (diag) { ANGLE_BODY(true) } else { ANGLE_BODY(false) }

  float asum = blk_sum(acc, s4, t);
  if (t == 0) ws[ANG_OFF + blockIdx.y * UP64 + blockIdx.x] = asum;

  if (blockIdx.y == 0) {  // fused dist-huber over this (i,j) tile
    float ssum = 0.f, tsum = 0.f;
    for (int i = t; i < UP16; i += 256) ssum += ws[DSUM_OFF + i];
    for (int i = t; i < UP16; i += 256) tsum += ws[DSUM_OFF + UP16 + i];
    ssum = blk_sum(ssum, s4, t);
    tsum = blk_sum(tsum, s4, t);
    float inv_ms = (float)NOFF / ssum;
    float inv_mt = (float)NOFF / tsum;
    float sqsi[4], sqti[4], sqsj[4], sqtj[4];
#pragma unroll
    for (int r = 0; r < 4; ++r) {
      sqsi[r] = sqs[i0 + ty * 4 + r];
      sqti[r] = sqt[i0 + ty * 4 + r];
      sqsj[r] = sqs[j0 + tx * 4 + r];
      sqtj[r] = sqt[j0 + tx * 4 + r];
    }
    float dacc = 0.f;
#pragma unroll
    for (int r = 0; r < 4; ++r)
#pragma unroll
      for (int c = 0; c < 4; ++c) {
        float d2s = sqsi[r] + sqsj[c] - 2.f * ps[r][c];
        float d2t = sqti[r] + sqtj[c] - 2.f * pt[r][c];
        float ds = sqrtf(fmaxf(d2s, 1e-12f)) * inv_ms;
        float dt = sqrtf(fmaxf(d2t, 1e-12f)) * inv_mt;
        float a = fabsf(ds - dt);
        if (diag) a = (ty * 4 + r < tx * 4 + c) ? a : 0.f;
        float mm = fminf(a, 1.f);
        dacc = fmaf(mm, fmaf(-0.5f, mm, a), dacc);
      }
    float dsum2 = blk_sum(dacc, s4, t);
    if (t == 0) ws[DIST_OFF + blockIdx.x] = dsum2;
  }
}

// K4: final reduce + combine
__global__ __launch_bounds__(256) void k_final(const float* __restrict__ ws,
                                               float* __restrict__ out) {
  __shared__ float s4[4];
  int t = threadIdx.x;
  float h = 0.f;
  for (int i = t; i < B; i += 256) h += ws[HARD_OFF + i];
  float a = 0.f;
  for (int i = t; i < UP64 * 48; i += 256) a += ws[ANG_OFF + i];
  float d = 0.f;
  for (int i = t; i < UP64; i += 256) d += ws[DIST_OFF + i];
  h = blk_sum(h, s4, t);
  a = blk_sum(a, s4, t);
  d = blk_sum(d, s4, t);
  if (t == 0)
    out[0] = h * (1.f / (float)B) + 2.f * d * (1.f / (float)NPAIR) +
             2.f * a * (1.f / 56623104.f);  // 384^3
}

extern "C" void kernel_launch(void* const* d_in, const int* in_sizes, int n_in,
                              void* d_out, int out_size, void* d_ws, size_t ws_size,
                              hipStream_t stream) {
  (void)in_sizes; (void)n_in; (void)out_size; (void)ws_size;
  const float* fs = (const float*)d_in[0];
  const float* ft = (const float*)d_in[1];
  const int* lab = (const int*)d_in[2];
  float* ws = (float*)d_ws;
  float* out = (float*)d_out;

  k_row<<<B, 256, 0, stream>>>(fs, ft, lab, ws);
  k_gram<<<150, 256, 0, stream>>>(fs, ft, ws);       // 600 waves = 600 upper 16x16 tiles x2 tensors
  k_angle<<<dim3(UP64, 48), 256, 0, stream>>>(ws);   // 21 upper 64x64 tiles x 48 b-groups
  k_final<<<1, 256, 0, stream>>>(ws, out);
}